// Round 8
// baseline (743.416 us; speedup 1.0000x reference)
//
#include <hip/hip_runtime.h>
#include <hip/hip_fp16.h>
#include <hip/hip_cooperative_groups.h>

namespace cg = cooperative_groups;

// GCN: 100K nodes, 1.6M edges, 128 -> 128 -> 128 -> 64 (fp32 in/out)
// v9: ONE cooperative kernel for the entire pipeline (prep + 3 layers),
// grid.sync between phases. v8 accounting showed ~90us of the 401 total
// was inter-dispatch dead time (6 gaps x ~14us); phases here are the
// proven v8 kernels re-expressed as grid-stride loops at 768 blocks x
// 512 threads (launch_bounds(512,6): VGPR<=85, 3 blocks/CU = 24 waves/CU
// co-resident -- v6's coop failure was a 196-block grid at 8.9% occ).
// fused keeps the exact v3 16-node/256-thread tile as two independent
// halves per block; gemm drops LDS staging for direct 32B-run stores.

#define NN 100000
#define NE 1600000
#define TT (NE + NN)              // edges + self loops
#define BSH 9                      // bucket = dst >> 9 (512 nodes/bucket)
#define NBUCK ((NN + 511) / 512)   // 196
#define EPB1 4096                  // edges per partition chunk
#define NPB1 ((TT + EPB1 - 1) / EPB1)   // 416
#define SLOT 12288                 // slack per bucket (exp 8673, ~39 sigma)
#define GRID_BLOCKS 768

typedef _Float16 f16x8 __attribute__((ext_vector_type(8)));
typedef float f32x4 __attribute__((ext_vector_type(4)));

struct HotS { _Float16 Hs[2][16][136]; _Float16 Ds[2][16][136]; };
struct P2S  { int red[512]; int cnt[512]; int scn[512]; int cur[512]; int sbase; };
union SMU {
    int  hist[NBUCK];
    P2S  p2;
    HotS hot;
};

__device__ __forceinline__ void acc_add8(float* acc, float4 raw) {
    const __half2* h2 = reinterpret_cast<const __half2*>(&raw);
#pragma unroll
    for (int qq = 0; qq < 4; qq++) {
        float2 fv = __half22float2(h2[qq]);
        acc[2 * qq]     += fv.x;
        acc[2 * qq + 1] += fv.y;
    }
}

// ---- fused aggregate + next-layer GEMM phase (v3 tile, 2 halves/block) ----
// Per half (256 thr, 16 nodes): gather thread=(node,fchunk) serial edge
// loop unroll 4; h=relu(dinv*sum+bias)->Hs; 16x128 @ Wt MFMA; D scaled by
// dinv[row] -> Ds; coalesced f16x8 store.

template <int FOUT>
__device__ void fused_phase(SMU& sm,
                            const __half* __restrict__ XWh,
                            const int* __restrict__ rowptr,
                            const int* __restrict__ col,
                            const float* __restrict__ dinv,
                            const float* __restrict__ bias,
                            const _Float16* __restrict__ Wt,
                            __half* __restrict__ Yout) {
    const int tid  = threadIdx.x;
    const int half = tid >> 8;
    const int t256 = tid & 255;
    const int gsz  = gridDim.x;
    for (int tb = blockIdx.x; tb < NN / 32; tb += gsz) {
        const int v0 = (tb * 2 + half) * 16;
        __syncthreads();                 // Hs/Ds reuse guard across iters
        // ---- gather ----
        {
            const int lnode = t256 >> 4;
            const int f = t256 & 15;
            const int v = v0 + lnode;
            const int beg = rowptr[v];
            const int end = rowptr[v + 1];
            const float4* base = reinterpret_cast<const float4*>(XWh);
            float acc[8] = {0.f, 0.f, 0.f, 0.f, 0.f, 0.f, 0.f, 0.f};
#pragma unroll 4
            for (int e = beg; e < end; e++) {
                int u = col[e];
                float4 raw = base[(size_t)u * 16 + f];
                acc_add8(acc, raw);
            }
            const float dv = dinv[v];
            union { f16x8 v8; _Float16 e8[8]; } hu;
#pragma unroll
            for (int qq = 0; qq < 8; qq++) {
                float r = dv * acc[qq] + bias[f * 8 + qq];
                hu.e8[qq] = (_Float16)fmaxf(r, 0.f);
            }
            *reinterpret_cast<f16x8*>(&sm.hot.Hs[half][lnode][f * 8]) = hu.v8;
        }
        __syncthreads();
        // ---- GEMM: D[16xFOUT] = dinv[row] * (Hs[16x128] @ Wt^T) ----
        constexpr int TPW = FOUT / 64;   // col tiles per wave
        const int wave = t256 >> 6;
        const int lane = t256 & 63;
        const int m = lane & 15;
        const int q = lane >> 4;
        f32x4 gacc[TPW];
#pragma unroll
        for (int t = 0; t < TPW; t++) gacc[t] = (f32x4){0.f, 0.f, 0.f, 0.f};
#pragma unroll
        for (int kt = 0; kt < 128; kt += 32) {
            const int k0 = kt + q * 8;
            f16x8 av = *reinterpret_cast<const f16x8*>(&sm.hot.Hs[half][m][k0]);
#pragma unroll
            for (int t = 0; t < TPW; t++) {
                const int gc = (wave * TPW + t) * 16 + m;
                f16x8 bv = *reinterpret_cast<const f16x8*>(Wt + gc * 128 + k0);
                gacc[t] = __builtin_amdgcn_mfma_f32_16x16x32_f16(av, bv, gacc[t], 0, 0, 0);
            }
        }
#pragma unroll
        for (int r = 0; r < 4; r++) {
            const int lrow = q * 4 + r;
            const float s = dinv[v0 + lrow];
#pragma unroll
            for (int t = 0; t < TPW; t++)
                sm.hot.Ds[half][lrow][(wave * TPW + t) * 16 + m] =
                    (_Float16)(s * gacc[t][r]);
        }
        __syncthreads();
        constexpr int CH = FOUT / 8;
        for (int i2 = t256; i2 < 16 * CH; i2 += 256) {
            int lrow = i2 / CH, c = i2 % CH;
            *reinterpret_cast<f16x8*>(Yout + (size_t)(v0 + lrow) * FOUT + c * 8) =
                *reinterpret_cast<const f16x8*>(&sm.hot.Ds[half][lrow][c * 8]);
        }
    }
}

// ---------------- the mega kernel ----------------

__global__ __launch_bounds__(512, 6) void mega(
        const float* __restrict__ x, const int* __restrict__ ei,
        const float* __restrict__ W1, const float* __restrict__ b1,
        const float* __restrict__ W2, const float* __restrict__ b2,
        const float* __restrict__ W3, const float* __restrict__ b3,
        _Float16* __restrict__ Wt1, _Float16* __restrict__ Wt2,
        _Float16* __restrict__ Wt3,
        int* __restrict__ gcursor, int* __restrict__ rowptr,
        float* __restrict__ dinv, int* __restrict__ part,
        int* __restrict__ col,
        __half* __restrict__ xwh1, __half* __restrict__ xwh2,
        float* __restrict__ out) {
    cg::grid_group grid = cg::this_grid();
    __shared__ SMU sm;
    const int tid = threadIdx.x;
    const int gsz = gridDim.x;

    // ---- phase 0: W pre-transpose fp32->fp16, zero gcursor, sentinels ----
    {
        int idx = blockIdx.x * 512 + tid;
        if (idx < 16384) {
            Wt1[(idx % 128) * 128 + idx / 128] = (_Float16)W1[idx];
        } else if (idx < 32768) {
            int i = idx - 16384;
            Wt2[(i % 128) * 128 + i / 128] = (_Float16)W2[i];
        } else if (idx < 40960) {
            int i = idx - 32768;
            Wt3[(i % 64) * 128 + i / 64] = (_Float16)W3[i];
        }
        if (idx < NBUCK) gcursor[idx] = 0;
        if (idx == 0) rowptr[NN] = TT;
    }
    grid.sync();

    // ---- phase 1: single-pass slack partition (v8 p1, 416 chunks) ----
    // record = src | (dst & 511) << 17
    for (int c = blockIdx.x; c < NPB1; c += gsz) {
        __syncthreads();                 // hist reuse guard
        for (int b = tid; b < NBUCK; b += 512) sm.hist[b] = 0;
        __syncthreads();
        const int base = c * EPB1;
        for (int i = tid; i < EPB1; i += 512) {
            int e = base + i;
            if (e >= TT) break;
            int d = (e < NE) ? ei[NE + e] : (e - NE);
            atomicAdd(&sm.hist[d >> BSH], 1);
        }
        __syncthreads();
        for (int b = tid; b < NBUCK; b += 512) {
            int cnt = sm.hist[b];
            sm.hist[b] = cnt ? atomicAdd(&gcursor[b], cnt) : 0;   // reserve
        }
        __syncthreads();
        for (int i = tid; i < EPB1; i += 512) {
            int e = base + i;
            if (e >= TT) break;
            int s, d;
            if (e < NE) { s = ei[e]; d = ei[NE + e]; }
            else        { s = d = e - NE; }
            int bk = d >> BSH;
            int pos = atomicAdd(&sm.hist[bk], 1);
            part[bk * SLOT + pos] = s | ((d & 511) << 17);
        }
    }
    grid.sync();

    // ---- phase 2: bucket-local rowptr/dinv + counting sort (v8 p2) ----
    for (int b = blockIdx.x; b < NBUCK; b += gsz) {
        const int v0 = b << BSH;
        const int nv = min(512, NN - v0);
        const int nrec = gcursor[b];
        const int* bp = part + (size_t)b * SLOT;
        sm.p2.red[tid] = (tid < b) ? gcursor[tid] : 0;
        sm.p2.cnt[tid] = 0;
        __syncthreads();
        for (int off = 256; off > 0; off >>= 1) {
            if (tid < off) sm.p2.red[tid] += sm.p2.red[tid + off];
            __syncthreads();
        }
        if (tid == 0) sm.p2.sbase = sm.p2.red[0];
        for (int i = tid; i < nrec; i += 512)
            atomicAdd(&sm.p2.cnt[((unsigned)bp[i]) >> 17], 1);
        __syncthreads();
        const int base = sm.p2.sbase;
        sm.p2.scn[tid] = sm.p2.cnt[tid];
        __syncthreads();
        for (int off = 1; off < 512; off <<= 1) {
            int a = (tid >= off) ? sm.p2.scn[tid - off] : 0;
            __syncthreads();
            sm.p2.scn[tid] += a;
            __syncthreads();
        }
        if (tid < nv) {
            int excl = sm.p2.scn[tid] - sm.p2.cnt[tid];
            rowptr[v0 + tid] = base + excl;
            dinv[v0 + tid] = rsqrtf((float)sm.p2.cnt[tid]);  // deg >= 1
            sm.p2.cur[tid] = base + excl;
        }
        __syncthreads();
        for (int i = tid; i < nrec; i += 512) {
            int r = bp[i];
            int pos = atomicAdd(&sm.p2.cur[((unsigned)r) >> 17], 1);
            col[pos] = r & 0x1FFFF;
        }
    }
    grid.sync();

    // ---- phase 3: layer-1 GEMM, xwh1 = dinv * (x @ W1), direct stores ----
    // 8 waves = 128 rows/block; D-frag 16-lane runs give 32B store runs.
    for (int tb = blockIdx.x; tb < (NN + 127) / 128; tb += gsz) {
        const int wave = tid >> 6;
        const int lane = tid & 63;
        const int m = lane & 15;
        const int q = lane >> 4;
        const int grow0 = tb * 128;
        const int row = grow0 + wave * 16 + m;
        const bool rok = row < NN;
        f32x4 acc[8];
#pragma unroll
        for (int t = 0; t < 8; t++) acc[t] = (f32x4){0.f, 0.f, 0.f, 0.f};
#pragma unroll
        for (int kt = 0; kt < 128; kt += 32) {
            const int k0 = kt + q * 8;
            union { f16x8 v; _Float16 e[8]; } au;
            if (rok) {
                float4 x0 = *reinterpret_cast<const float4*>(x + (size_t)row * 128 + k0);
                float4 x1 = *reinterpret_cast<const float4*>(x + (size_t)row * 128 + k0 + 4);
                au.e[0] = (_Float16)x0.x; au.e[1] = (_Float16)x0.y;
                au.e[2] = (_Float16)x0.z; au.e[3] = (_Float16)x0.w;
                au.e[4] = (_Float16)x1.x; au.e[5] = (_Float16)x1.y;
                au.e[6] = (_Float16)x1.z; au.e[7] = (_Float16)x1.w;
            } else {
#pragma unroll
                for (int j = 0; j < 8; j++) au.e[j] = (_Float16)0.f;
            }
#pragma unroll
            for (int t = 0; t < 8; t++) {
                f16x8 bf = *reinterpret_cast<const f16x8*>(Wt1 + (t * 16 + m) * 128 + k0);
                acc[t] = __builtin_amdgcn_mfma_f32_16x16x32_f16(au.v, bf, acc[t], 0, 0, 0);
            }
        }
        _Float16* Y = reinterpret_cast<_Float16*>(xwh1);
#pragma unroll
        for (int r = 0; r < 4; r++) {
            int gr = grow0 + wave * 16 + q * 4 + r;
            if (gr < NN) {
                float s = dinv[gr];
#pragma unroll
                for (int t = 0; t < 8; t++)
                    Y[(size_t)gr * 128 + t * 16 + m] = (_Float16)(s * acc[t][r]);
            }
        }
    }
    grid.sync();

    // ---- phase 4: fused agg+GEMM layer 2: xwh2 = dinv*(relu(agg xwh1)@W2) ----
    fused_phase<128>(sm, xwh1, rowptr, col, dinv, b1, Wt2, xwh2);
    grid.sync();

    // ---- phase 5: fused agg+GEMM layer 3: xwh1 = dinv*(relu(agg xwh2)@W3) ----
    fused_phase<64>(sm, xwh2, rowptr, col, dinv, b2, Wt3, xwh1);
    grid.sync();

    // ---- phase 6: final aggregate, fp32 out + bias, no relu ----
    for (int tb = blockIdx.x; tb < (NN + 63) / 64; tb += gsz) {
        const int v = tb * 64 + (tid >> 3);
        const int f = tid & 7;
        if (v < NN) {
            const int beg = rowptr[v];
            const int end = rowptr[v + 1];
            const float4* base = reinterpret_cast<const float4*>(xwh1);
            float acc[8] = {0.f, 0.f, 0.f, 0.f, 0.f, 0.f, 0.f, 0.f};
#pragma unroll 4
            for (int e = beg; e < end; e++) {
                int u = col[e];
                float4 raw = base[(size_t)u * 8 + f];
                acc_add8(acc, raw);
            }
            const float dv = dinv[v];
            float r[8];
#pragma unroll
            for (int qq = 0; qq < 8; qq++)
                r[qq] = dv * acc[qq] + b3[f * 8 + qq];
            float* op = out + (size_t)v * 64 + f * 8;
            *reinterpret_cast<float4*>(op)     = make_float4(r[0], r[1], r[2], r[3]);
            *reinterpret_cast<float4*>(op + 4) = make_float4(r[4], r[5], r[6], r[7]);
        }
    }
}

// ---------------- launch ----------------

extern "C" void kernel_launch(void* const* d_in, const int* in_sizes, int n_in,
                              void* d_out, int out_size, void* d_ws, size_t ws_size,
                              hipStream_t stream) {
    const float* x  = (const float*)d_in[0];
    const int*   ei = (const int*)d_in[1];
    const float* W1 = (const float*)d_in[2];
    const float* b1 = (const float*)d_in[3];
    const float* W2 = (const float*)d_in[4];
    const float* b2 = (const float*)d_in[5];
    const float* W3 = (const float*)d_in[6];
    const float* b3 = (const float*)d_in[7];
    float* out = (float*)d_out;

    char* p = (char*)d_ws;
    int*      rowptr  = (int*)p;       p += 400016;
    float*    dinv    = (float*)p;     p += 400000;
    int*      gcursor = (int*)p;       p += 1024;
    _Float16* Wt1     = (_Float16*)p;  p += 32768;
    _Float16* Wt2     = (_Float16*)p;  p += 32768;
    _Float16* Wt3     = (_Float16*)p;  p += 16384;
    int*      part    = (int*)p;       p += (size_t)NBUCK * SLOT * 4; // 9.6 MB
    int*      col     = (int*)p;       p += (size_t)TT * 4;           // 6.8 MB
    __half*   xwh1    = (__half*)p;    p += (size_t)NN * 128 * 2;     // 25.6 MB
    __half*   xwh2    = (__half*)p;                                    // 25.6 MB

    // grid sizing: want 3 blocks/CU (launch_bounds guarantees); clamp by
    // runtime occupancy so the cooperative launch can never over-subscribe.
    static int s_grid = 0;
    if (s_grid == 0) {
        hipDeviceProp_t prop;
        hipGetDeviceProperties(&prop, 0);
        int nb = 0;
        hipOccupancyMaxActiveBlocksPerMultiprocessor(&nb, (const void*)mega, 512, 0);
        if (nb < 1) nb = 1;
        long g = (long)nb * prop.multiProcessorCount;
        if (g > GRID_BLOCKS) g = GRID_BLOCKS;
        s_grid = (int)g;
    }

    void* args[] = {(void*)&x, (void*)&ei,
                    (void*)&W1, (void*)&b1, (void*)&W2, (void*)&b2,
                    (void*)&W3, (void*)&b3,
                    (void*)&Wt1, (void*)&Wt2, (void*)&Wt3,
                    (void*)&gcursor, (void*)&rowptr, (void*)&dinv,
                    (void*)&part, (void*)&col,
                    (void*)&xwh1, (void*)&xwh2, (void*)&out};
    hipLaunchCooperativeKernel((void*)mega, dim3(s_grid), dim3(512),
                               args, 0, stream);
}

// Round 9
// 436.916 us; speedup vs baseline: 1.7015x; 1.7015x over previous
//
#include <hip/hip_runtime.h>
#include <hip/hip_fp16.h>

// GCN: 100K nodes, 1.6M edges, 128 -> 128 -> 128 -> 64 (fp32 in/out)
// v10 = v8 (401us, proven) with the layer-1 GEMM appended to p2's tail:
// partition_gemm (1024 thr, 196 blocks) does bucket rowptr/dinv/sort then
// computes xwh1 = dinv*(x@W1) for its own 512 rows (dinv already in LDS).
// Deletes one dispatch; p2 record loops run at 1024 threads (~8.5 iters).
// v9 mega-kernel reverted: persistent-block grid-stride + grid.sync made
// phases 3x slower (straggler serialization, no oversubscription backfill).

#define NN 100000
#define NE 1600000
#define TT (NE + NN)              // edges + self loops
#define BSH 9                      // bucket = dst >> 9 (512 nodes/bucket)
#define NBUCK ((NN + 511) / 512)   // 196
#define EPB1 8192                  // edges per partition block
#define NPB1 ((TT + EPB1 - 1) / EPB1)   // 208
#define SLOT 12288                 // slack per bucket (exp 8673, ~39 sigma)

typedef _Float16 f16x8 __attribute__((ext_vector_type(8)));
typedef float f32x4 __attribute__((ext_vector_type(4)));

// ------- W pre-transpose + zero gcursor + sentinels (replaces memset) -------

__global__ __launch_bounds__(256) void wt_conv_all(const float* __restrict__ W1,
                                                   const float* __restrict__ W2,
                                                   const float* __restrict__ W3,
                                                   _Float16* __restrict__ Wt1,
                                                   _Float16* __restrict__ Wt2,
                                                   _Float16* __restrict__ Wt3,
                                                   int* __restrict__ gcursor,
                                                   int* __restrict__ rowptr) {
    int idx = blockIdx.x * 256 + threadIdx.x;
    if (idx < 16384) {
        Wt1[(idx % 128) * 128 + idx / 128] = (_Float16)W1[idx];
    } else if (idx < 32768) {
        int i = idx - 16384;
        Wt2[(i % 128) * 128 + i / 128] = (_Float16)W2[i];
    } else if (idx < 40960) {
        int i = idx - 32768;
        Wt3[(i % 64) * 128 + i / 64] = (_Float16)W3[i];
    }
    if (idx < NBUCK) gcursor[idx] = 0;
    if (idx == 0) rowptr[NN] = TT;
}

// ---- single-pass partition: LDS hist -> bucket-space reserve -> scatter ----
// record = src | (dst & 511) << 17   (src < 2^17, local dst < 2^9)
// part is a slack layout: bucket b occupies part[b*SLOT .. b*SLOT+cnt_b).

__global__ __launch_bounds__(1024) void partition_p1(const int* __restrict__ ei,
                                                     int* __restrict__ gcursor,
                                                     int* __restrict__ part) {
    __shared__ int hist[NBUCK];
    const int tid = threadIdx.x;
    const int base = blockIdx.x * EPB1;
    for (int b = tid; b < NBUCK; b += 1024) hist[b] = 0;
    __syncthreads();
    for (int i = tid; i < EPB1; i += 1024) {
        int e = base + i;
        if (e >= TT) break;
        int d = (e < NE) ? ei[NE + e] : (e - NE);
        atomicAdd(&hist[d >> BSH], 1);
    }
    __syncthreads();
    for (int b = tid; b < NBUCK; b += 1024) {
        int cnt = hist[b];
        hist[b] = cnt ? atomicAdd(&gcursor[b], cnt) : 0;   // reserve run
    }
    __syncthreads();
    for (int i = tid; i < EPB1; i += 1024) {
        int e = base + i;
        if (e >= TT) break;
        int s, d;
        if (e < NE) { s = ei[e]; d = ei[NE + e]; }
        else        { s = d = e - NE; }
        int bk = d >> BSH;
        int pos = atomicAdd(&hist[bk], 1);
        part[bk * SLOT + pos] = s | ((d & 511) << 17);
    }
}

// -------- p2 + layer-1 GEMM tail. 1024 threads, one block per bucket. --------
// Part A (v8 p2): per-block prefix (196-wide reduce), bucket-local
// count/scan -> rowptr/dinv (also kept in LDS sdinv), counting sort -> col.
// Part B: xwh1[v0..v0+nv) = sdinv * (x @ W1) via 16x16x32 MFMA, 2 passes
// of 256 rows (16 waves x 16 rows), LDS-staged coalesced f16x8 stores.

__global__ __launch_bounds__(1024) void partition_gemm(
        const int* __restrict__ part,
        const int* __restrict__ gcnt,
        const float* __restrict__ x,
        const _Float16* __restrict__ Wt1,
        int* __restrict__ rowptr,
        float* __restrict__ dinv,
        int* __restrict__ col,
        __half* __restrict__ xwh1) {
    __shared__ int red[512];
    __shared__ int cnt[512];
    __shared__ int scn[512];
    __shared__ int cur[512];
    __shared__ float sdinv[512];
    __shared__ _Float16 Yl[256][136];   // 69.6 KB staging for GEMM stores
    __shared__ int sbase_s;
    const int b = blockIdx.x;
    const int v0 = b << BSH;
    const int nv = min(512, NN - v0);
    const int tid = threadIdx.x;
    const int nrec = gcnt[b];
    const int* bp = part + (size_t)b * SLOT;

    // ---- part A: rowptr / dinv / counting sort ----
    if (tid < 512) { red[tid] = (tid < b) ? gcnt[tid] : 0; cnt[tid] = 0; }
    __syncthreads();
    for (int off = 256; off > 0; off >>= 1) {
        if (tid < off) red[tid] += red[tid + off];
        __syncthreads();
    }
    if (tid == 0) sbase_s = red[0];
    for (int i = tid; i < nrec; i += 1024)
        atomicAdd(&cnt[((unsigned)bp[i]) >> 17], 1);
    __syncthreads();
    const int base = sbase_s;
    if (tid < 512) scn[tid] = cnt[tid];
    __syncthreads();
    for (int off = 1; off < 512; off <<= 1) {
        int a = (tid < 512 && tid >= off) ? scn[tid - off] : 0;
        __syncthreads();
        if (tid < 512) scn[tid] += a;
        __syncthreads();
    }
    if (tid < 512) {
        float dv_t = 0.f;
        if (tid < nv) {
            int excl = scn[tid] - cnt[tid];
            rowptr[v0 + tid] = base + excl;
            dv_t = rsqrtf((float)cnt[tid]);   // deg >= 1 (self loop)
            dinv[v0 + tid] = dv_t;
            cur[tid] = base + excl;
        }
        sdinv[tid] = dv_t;
    }
    __syncthreads();
    for (int i = tid; i < nrec; i += 1024) {
        int r = bp[i];
        int pos = atomicAdd(&cur[((unsigned)r) >> 17], 1);
        col[pos] = r & 0x1FFFF;
    }

    // ---- part B: GEMM tail for this bucket's rows ----
    const int wave = tid >> 6;        // 0..15
    const int lane = tid & 63;
    const int m = lane & 15;
    const int q = lane >> 4;
#pragma unroll 1
    for (int pass = 0; pass < 2; pass++) {
        const int rb = pass * 256;
        const int lr0 = wave * 16;
        const int j = rb + lr0 + m;           // bucket-local row (A operand)
        const int row = v0 + j;
        const bool rok = j < nv;
        f32x4 acc[8];
#pragma unroll
        for (int t = 0; t < 8; t++) acc[t] = (f32x4){0.f, 0.f, 0.f, 0.f};
#pragma unroll
        for (int kt = 0; kt < 128; kt += 32) {
            const int k0 = kt + q * 8;
            union { f16x8 v; _Float16 e[8]; } au;
            if (rok) {
                float4 x0 = *reinterpret_cast<const float4*>(x + (size_t)row * 128 + k0);
                float4 x1 = *reinterpret_cast<const float4*>(x + (size_t)row * 128 + k0 + 4);
                au.e[0] = (_Float16)x0.x; au.e[1] = (_Float16)x0.y;
                au.e[2] = (_Float16)x0.z; au.e[3] = (_Float16)x0.w;
                au.e[4] = (_Float16)x1.x; au.e[5] = (_Float16)x1.y;
                au.e[6] = (_Float16)x1.z; au.e[7] = (_Float16)x1.w;
            } else {
#pragma unroll
                for (int jj = 0; jj < 8; jj++) au.e[jj] = (_Float16)0.f;
            }
#pragma unroll
            for (int t = 0; t < 8; t++) {
                f16x8 bf = *reinterpret_cast<const f16x8*>(Wt1 + (t * 16 + m) * 128 + k0);
                acc[t] = __builtin_amdgcn_mfma_f32_16x16x32_f16(au.v, bf, acc[t], 0, 0, 0);
            }
        }
#pragma unroll
        for (int r = 0; r < 4; r++) {
            const int lr = lr0 + q * 4 + r;
            const float s = sdinv[rb + lr];   // 0 for rows >= nv
#pragma unroll
            for (int t = 0; t < 8; t++)
                Yl[lr][t * 16 + m] = (_Float16)(s * acc[t][r]);
        }
        __syncthreads();
        for (int i2 = tid; i2 < 256 * 16; i2 += 1024) {
            int lr = i2 >> 4, c = i2 & 15;
            int jj = rb + lr;
            if (jj < nv)
                *reinterpret_cast<f16x8*>(xwh1 + (size_t)(v0 + jj) * 128 + c * 8) =
                    *reinterpret_cast<const f16x8*>(&Yl[lr][c * 8]);
        }
        __syncthreads();   // Yl reuse guard
    }
}

// ---------------- helper ----------------

__device__ __forceinline__ void acc_add8(float* acc, float4 raw) {
    const __half2* h2 = reinterpret_cast<const __half2*>(&raw);
#pragma unroll
    for (int qq = 0; qq < 4; qq++) {
        float2 fv = __half22float2(h2[qq]);
        acc[2 * qq]     += fv.x;
        acc[2 * qq + 1] += fv.y;
    }
}

// ---------------- fused aggregate + next-layer GEMM (v3, proven) -------------
// Block = 256 thr = 16 nodes. Gather: thread = (node tid/16, f-chunk
// tid%16), serial edge loop unroll 4 -> 4 independent 16B gathers in
// flight per thread. h = relu(dinv[v]*sum + bias) -> LDS. GEMM: 16x128
// @ Wt (16x16x32 MFMA), D scaled by dinv[row] (prescale for the next
// gather), coalesced f16x8 store.

template <int FOUT>
__global__ __launch_bounds__(256) void fused_agg_gemm(
        const __half* __restrict__ XWh,      // [NN][128] fp16, prescaled
        const int* __restrict__ rowptr,
        const int* __restrict__ col,
        const float* __restrict__ dinv,
        const float* __restrict__ bias,      // [128]
        const _Float16* __restrict__ Wt,     // [FOUT][128] fp16
        __half* __restrict__ Yout) {         // [NN][FOUT] fp16, prescaled
    __shared__ _Float16 Hs[16][136];
    __shared__ _Float16 Ds[16][FOUT + 8];

    const int tid = threadIdx.x;
    const int v0 = blockIdx.x * 16;

    // ---- gather phase ----
    {
        const int lnode = tid >> 4;       // 0..15
        const int f = tid & 15;           // 16B chunk
        const int v = v0 + lnode;
        const int beg = rowptr[v];
        const int end = rowptr[v + 1];
        const float4* base = reinterpret_cast<const float4*>(XWh);
        float acc[8] = {0.f, 0.f, 0.f, 0.f, 0.f, 0.f, 0.f, 0.f};
#pragma unroll 4
        for (int e = beg; e < end; e++) {
            int u = col[e];
            float4 raw = base[(size_t)u * 16 + f];
            acc_add8(acc, raw);
        }
        const float dv = dinv[v];
        union { f16x8 v8; _Float16 e8[8]; } hu;
#pragma unroll
        for (int qq = 0; qq < 8; qq++) {
            float r = dv * acc[qq] + bias[f * 8 + qq];
            hu.e8[qq] = (_Float16)fmaxf(r, 0.f);
        }
        *reinterpret_cast<f16x8*>(&Hs[lnode][f * 8]) = hu.v8;
    }
    __syncthreads();

    // ---- GEMM phase: D[16xFOUT] = dinv[row] * (Hs[16x128] @ Wt^T) ----
    constexpr int TPW = FOUT / 64;    // col tiles per wave: 2 (F=128) or 1
    const int wave = tid >> 6;
    const int lane = tid & 63;
    const int m = lane & 15;
    const int q = lane >> 4;
    f32x4 gacc[TPW];
#pragma unroll
    for (int t = 0; t < TPW; t++) gacc[t] = (f32x4){0.f, 0.f, 0.f, 0.f};
#pragma unroll
    for (int kt = 0; kt < 128; kt += 32) {
        const int k0 = kt + q * 8;
        f16x8 av = *reinterpret_cast<const f16x8*>(&Hs[m][k0]);
#pragma unroll
        for (int t = 0; t < TPW; t++) {
            const int gc = (wave * TPW + t) * 16 + m;
            f16x8 bv = *reinterpret_cast<const f16x8*>(Wt + gc * 128 + k0);
            gacc[t] = __builtin_amdgcn_mfma_f32_16x16x32_f16(av, bv, gacc[t], 0, 0, 0);
        }
    }
#pragma unroll
    for (int r = 0; r < 4; r++) {
        const int lrow = q * 4 + r;
        const float s = dinv[v0 + lrow];
#pragma unroll
        for (int t = 0; t < TPW; t++)
            Ds[lrow][(wave * TPW + t) * 16 + m] = (_Float16)(s * gacc[t][r]);
    }
    __syncthreads();
    constexpr int CH = FOUT / 8;
    for (int i2 = tid; i2 < 16 * CH; i2 += 256) {
        int lrow = i2 / CH, c = i2 % CH;
        *reinterpret_cast<f16x8*>(Yout + (size_t)(v0 + lrow) * FOUT + c * 8) =
            *reinterpret_cast<const f16x8*>(&Ds[lrow][c * 8]);
    }
}

// -------- final aggregate: F=64, fp32 out, bias, no relu (round-0 kernel) ----

__global__ __launch_bounds__(256) void agg_final(
        const __half* __restrict__ XWh,      // [NN][64] fp16, prescaled
        const int* __restrict__ rowptr,
        const int* __restrict__ col,
        const float* __restrict__ dinv,
        const float* __restrict__ bias,      // [64]
        float* __restrict__ out) {
    constexpr int TPN = 8;            // 64/8 chunks of 16B
    constexpr int NPB = 256 / TPN;    // 32 nodes/block
    const int v = blockIdx.x * NPB + threadIdx.x / TPN;
    const int f = threadIdx.x % TPN;
    const int beg = rowptr[v];
    const int end = rowptr[v + 1];
    const float4* base = reinterpret_cast<const float4*>(XWh);
    float acc[8] = {0.f, 0.f, 0.f, 0.f, 0.f, 0.f, 0.f, 0.f};
#pragma unroll 4
    for (int e = beg; e < end; e++) {
        int u = col[e];
        float4 raw = base[(size_t)u * TPN + f];
        acc_add8(acc, raw);
    }
    const float dv = dinv[v];
    float r[8];
#pragma unroll
    for (int q = 0; q < 8; q++)
        r[q] = dv * acc[q] + bias[f * 8 + q];
    float* op = out + (size_t)v * 64 + f * 8;
    *reinterpret_cast<float4*>(op)     = make_float4(r[0], r[1], r[2], r[3]);
    *reinterpret_cast<float4*>(op + 4) = make_float4(r[4], r[5], r[6], r[7]);
}

// ---------------- launch ----------------

extern "C" void kernel_launch(void* const* d_in, const int* in_sizes, int n_in,
                              void* d_out, int out_size, void* d_ws, size_t ws_size,
                              hipStream_t stream) {
    const float* x  = (const float*)d_in[0];
    const int*   ei = (const int*)d_in[1];
    const float* W1 = (const float*)d_in[2];
    const float* b1 = (const float*)d_in[3];
    const float* W2 = (const float*)d_in[4];
    const float* b2 = (const float*)d_in[5];
    const float* W3 = (const float*)d_in[6];
    const float* b3 = (const float*)d_in[7];
    float* out = (float*)d_out;

    char* p = (char*)d_ws;
    int*      rowptr  = (int*)p;       p += 400016;
    float*    dinv    = (float*)p;     p += 400000;
    int*      gcursor = (int*)p;       p += 1024;
    _Float16* Wt1     = (_Float16*)p;  p += 32768;
    _Float16* Wt2     = (_Float16*)p;  p += 32768;
    _Float16* Wt3     = (_Float16*)p;  p += 16384;
    int*      part    = (int*)p;       p += (size_t)NBUCK * SLOT * 4; // 9.6 MB
    int*      col     = (int*)p;       p += (size_t)TT * 4;           // 6.8 MB
    __half*   xwh1    = (__half*)p;    p += (size_t)NN * 128 * 2;     // 25.6 MB
    __half*   xwh2    = (__half*)p;                                    // 25.6 MB
    __half*   xwh3    = xwh1;          // layer-3 input reuses xwh1's space

    wt_conv_all<<<160, 256, 0, stream>>>(W1, W2, W3, Wt1, Wt2, Wt3,
                                         gcursor, rowptr);
    partition_p1<<<NPB1, 1024, 0, stream>>>(ei, gcursor, part);
    // p2 + layer-1 GEMM fused: rowptr/dinv/col, then xwh1 = dinv * (x @ W1)
    partition_gemm<<<NBUCK, 1024, 0, stream>>>(part, gcursor, x, Wt1,
                                               rowptr, dinv, col, xwh1);

    const int fb = NN / 16;          // 6250 (exact)
    // fused: h1 = relu(dinv*agg(xwh1)+b1); xwh2 = dinv * (h1 @ W2)
    fused_agg_gemm<128><<<fb, 256, 0, stream>>>(xwh1, rowptr, col, dinv, b1,
                                                Wt2, xwh2);
    // fused: h2 = relu(dinv*agg(xwh2)+b2); xwh3 = dinv * (h2 @ W3)
    fused_agg_gemm<64><<<fb, 256, 0, stream>>>(xwh2, rowptr, col, dinv, b2,
                                               Wt3, xwh3);
    // final: out = dinv*agg(xwh3) + b3
    agg_final<<<NN / 32, 256, 0, stream>>>(xwh3, rowptr, col, dinv, b3, out);
}